// Round 14
// baseline (40.549 us; speedup 1.0000x reference)
//
#include <hip/hip_runtime.h>

// B=64, H=W=512, K=7, VALID conv -> 506x506.
// v13 = v12 (guard-free shifted tiling, fully-used float4 loads, SGPR
// weights) + EXPLICIT 3-deep software pipeline.
// v12 post-mortem: compiler chose 36 VGPR and serialized each row
// (3 loads -> vmcnt(0) -> 196 FMA): MLP=3 then full drain -> per-wave duty
// ~6%, SIMD idle 77%. Rotating 3-row register buffer keeps 9 float4 loads
// in flight per wave; full unroll keeps all indices static (no scratch);
// the compiler's per-register waitcnt tracking yields counted vmcnt waits.
// No __launch_bounds__ cap (v3/v4/v7 spill disasters). Plain stores
// (v10's NT stores doubled WRITE_SIZE).
#define HW 512
#define OW 506

__device__ __forceinline__ float elem(const float4 (&b)[3], int e) {
    // e is compile-time after unroll -> folds to a direct register ref
    const float4& q = b[e >> 2];
    switch (e & 3) {
        case 0:  return q.x;
        case 1:  return q.y;
        case 2:  return q.z;
        default: return q.w;
    }
}

template<int SH>
__device__ __forceinline__ void conv_pipe(const float* __restrict__ p0,
                                          const float (&wv)[49],
                                          float (&acc)[16]) {
    float4 buf[3][3];   // rotating 3-row window buffer, statically indexed

    // ---- prologue: issue rows 0..2 (9 float4 loads in flight) ----
#pragma unroll
    for (int r = 0; r < 3; ++r) {
        const float* p = p0 + r * HW;
        buf[r][0] = *reinterpret_cast<const float4*>(p);
        buf[r][1] = *reinterpret_cast<const float4*>(p + 4);
        buf[r][2] = *reinterpret_cast<const float4*>(p + 8);
    }

    // ---- steady state: compute row ir, then refill its slot with ir+3 ----
#pragma unroll
    for (int ir = 0; ir < 10; ++ir) {
        const int slot = ir % 3;                 // static after unroll

#pragma unroll
        for (int kr = 0; kr < 7; ++kr) {
            const int s = ir - kr;               // static after unroll
            if (s >= 0 && s < 4) {
#pragma unroll
                for (int kc = 0; kc < 7; ++kc) {
                    const float wk = wv[kr * 7 + kc];
#pragma unroll
                    for (int j = 0; j < 4; ++j)
                        acc[s * 4 + j] = fmaf(wk, elem(buf[slot], SH + kc + j),
                                              acc[s * 4 + j]);
                }
            }
        }

        if (ir + 3 < 10) {                       // refill freed slot
            const float* p = p0 + (ir + 3) * HW;
            buf[slot][0] = *reinterpret_cast<const float4*>(p);
            buf[slot][1] = *reinterpret_cast<const float4*>(p + 4);
            buf[slot][2] = *reinterpret_cast<const float4*>(p + 8);
        }
    }
}

__global__ __launch_bounds__(256) void conv7x7_v13(
    const float* __restrict__ in,      // [64][512][512]
    const float* __restrict__ weight,  // [7][7]
    const float* __restrict__ bias,    // [1]
    float* __restrict__ out)           // [64][506][506]
{
    const int tid  = threadIdx.x;
    const int lane = tid & 63;
    const int w    = tid >> 6;
    const int bx   = blockIdx.x;                // 0 or 1
    const int x0   = bx ? 250 : 0;              // tiles cover 0..255, 250..505
    const int y0   = min((int)blockIdx.y * 16, OW - 16);  // shifted last tile
    const int yb   = y0 + w * 4;                // wave's first output row (<=502)
    const int b    = blockIdx.z;

    // ---- weights + bias -> SGPRs (uniform, statically indexed) ----
    float wv[49];
#pragma unroll
    for (int i = 0; i < 49; ++i)
        wv[i] = __uint_as_float(__builtin_amdgcn_readfirstlane(__float_as_uint(weight[i])));
    const float bv = __uint_as_float(__builtin_amdgcn_readfirstlane(__float_as_uint(bias[0])));

    const float* __restrict__ ib = in + (size_t)b * (HW * HW);

    const int cb = x0 + 4 * lane;               // first output col
    // Aligned load base: bx=0 -> cb (==0 mod 4), window [cb..cb+11] <= 263.
    //                    bx=1 -> cb-2 (==0 mod 4), window [cb-2..cb+9] <= 511.
    const float* p0 = ib + (size_t)yb * HW + (cb - (bx ? 2 : 0));

    float acc[16];
#pragma unroll
    for (int i = 0; i < 16; ++i) acc[i] = 0.f;

    if (bx == 0) conv_pipe<0>(p0, wv, acc);     // uniform SGPR branch
    else         conv_pipe<2>(p0, wv, acc);

    // ---- store: 4 rows x 4 cols, two float2 per row, unguarded ----
    float* __restrict__ outb = out + (size_t)b * (OW * OW);
#pragma unroll
    for (int s = 0; s < 4; ++s) {
        float* orow = outb + (size_t)(yb + s) * OW + cb;   // cb even -> 8B aligned
        *reinterpret_cast<float2*>(orow) =
            make_float2(acc[s * 4 + 0] + bv, acc[s * 4 + 1] + bv);
        *reinterpret_cast<float2*>(orow + 2) =
            make_float2(acc[s * 4 + 2] + bv, acc[s * 4 + 3] + bv);
    }
}

extern "C" void kernel_launch(void* const* d_in, const int* in_sizes, int n_in,
                              void* d_out, int out_size, void* d_ws, size_t ws_size,
                              hipStream_t stream) {
    const float* enc_x  = (const float*)d_in[0];
    const float* weight = (const float*)d_in[1];
    const float* bias   = (const float*)d_in[2];
    float* outp         = (float*)d_out;

    // x: 2 overlapping 256-col tiles; y: 32 tiles of 16 rows (last shifted);
    // z: 64 images. 4096 blocks = 16/CU exactly.
    dim3 grid(2, 32, 64);
    dim3 block(256);
    hipLaunchKernelGGL(conv7x7_v13, grid, block, 0, stream,
                       enc_x, weight, bias, outp);
}